// Round 3
// baseline (323.124 us; speedup 1.0000x reference)
//
#include <hip/hip_runtime.h>
#include <hip/hip_fp16.h>

#define NN 512          // N == M
#define DD 64           // feature dim
#define BIGF 1e10f
#define INV_LN2 1.44269504088896340736f
#define LN2 0.69314718055994530942f

// ======================= Phase 1: delta -> skewed fp16 layout =======================
// skew[b][d][i] (half) at  skew + ((size_t)b*1023 + d)*512 + i, value = delta/ln2.
// Only valid i are written; DP masks the rest.
#define TS 128          // tile size (i and j)
#define XST 68          // LDS stage row stride (floats)
#define ZST 132         // LDS Zs row stride (floats)

__global__ __launch_bounds__(256, 2)
void delta_kernel(const float* __restrict__ X, const float* __restrict__ Y,
                  __half* __restrict__ skew)
{
  __shared__ __align__(16) char smem[TS * XST * 4 * 2];   // 69632 B
  __shared__ float norms[2 * TS];                          // xx | yy
  float* Xs = (float*)smem;               // [TS][XST]
  float* Ys = Xs + TS * XST;              // [TS][XST]
  float* Zs = (float*)smem;               // [TS][ZST] overlays Xs|Ys

  const int b  = blockIdx.z;
  const int i0 = blockIdx.y * TS;
  const int j0 = blockIdx.x * TS;
  const int tid = threadIdx.x;

  const float4* X4 = (const float4*)(X + ((size_t)b * NN + i0) * DD);
  const float4* Y4 = (const float4*)(Y + ((size_t)b * NN + j0) * DD);
  #pragma unroll
  for (int q = 0; q < 8; ++q) {
    int idx = tid + 256 * q;          // 0..2047
    int r = idx >> 4, c4 = idx & 15;
    *(float4*)&Xs[r * XST + 4 * c4] = X4[idx];
    *(float4*)&Ys[r * XST + 4 * c4] = Y4[idx];
  }
  __syncthreads();

  {
    const float* row = (tid < TS) ? &Xs[tid * XST] : &Ys[(tid - TS) * XST];
    float s = 0.f;
    #pragma unroll
    for (int k4 = 0; k4 < 16; ++k4) {
      float4 v = *(const float4*)&row[4 * k4];
      s += v.x * v.x + v.y * v.y + v.z * v.z + v.w * v.w;
    }
    norms[tid] = s;
  }

  const int iB = (tid >> 4) * 8;
  const int jB = (tid & 15) * 8;
  float acc[8][8];
  #pragma unroll
  for (int a = 0; a < 8; ++a)
    #pragma unroll
    for (int c = 0; c < 8; ++c) acc[a][c] = 0.f;

  #pragma unroll
  for (int kc = 0; kc < 16; ++kc) {
    float4 xv[8], yv[8];
    #pragma unroll
    for (int a = 0; a < 8; ++a) xv[a] = *(const float4*)&Xs[(iB + a) * XST + 4 * kc];
    #pragma unroll
    for (int c = 0; c < 8; ++c) yv[c] = *(const float4*)&Ys[(jB + c) * XST + 4 * kc];
    #pragma unroll
    for (int a = 0; a < 8; ++a)
      #pragma unroll
      for (int c = 0; c < 8; ++c) {
        float4 xa = xv[a], yc = yv[c];
        acc[a][c] = fmaf(xa.x, yc.x,
                    fmaf(xa.y, yc.y,
                    fmaf(xa.z, yc.z,
                    fmaf(xa.w, yc.w, acc[a][c]))));
      }
  }
  __syncthreads();   // Xs/Ys dead; norms visible

  #pragma unroll
  for (int a = 0; a < 8; ++a) {
    float xxv = norms[iB + a];
    #pragma unroll
    for (int c4 = 0; c4 < 2; ++c4) {
      float4 z;
      z.x = fmaf(-2.f, acc[a][4*c4+0], xxv + norms[TS + jB + 4*c4+0]);
      z.y = fmaf(-2.f, acc[a][4*c4+1], xxv + norms[TS + jB + 4*c4+1]);
      z.z = fmaf(-2.f, acc[a][4*c4+2], xxv + norms[TS + jB + 4*c4+2]);
      z.w = fmaf(-2.f, acc[a][4*c4+3], xxv + norms[TS + jB + 4*c4+3]);
      *(float4*)&Zs[(iB + a) * ZST + jB + 4*c4] = z;
    }
  }
  __syncthreads();

  // per-diagonal segments, converted to fp16 * (1/ln2), coalesced 2B stores
  const int lane = tid & 63, w = tid >> 6;
  __half* skb = skew + (size_t)b * 1023 * NN;
  const int dbase = i0 + j0;
  for (int e = w; e < 2 * TS - 1; e += 4) {
    int lo = (e > TS - 1) ? e - (TS - 1) : 0;
    int hi = (e < TS - 1) ? e : TS - 1;
    for (int il = lo + lane; il <= hi; il += 64) {
      float v = Zs[il * ZST + (e - il)];
      skb[(size_t)(dbase + e) * NN + (i0 + il)] = __float2half(v * INV_LN2);
    }
  }
}

// ======================= Phase 2: wave-staggered register DP =======================
// 256 threads = 4 waves; thread t owns rows 2t (lo), 2t+1 (hi).
// Wave w runs CW*w diagonals behind wave w-1; cross-wave boundary values flow
// through a 64-deep circular LDS buffer; one barrier per CW diagonals.
// All DP values are in log2 units (delta/ln2); final loss scaled by ln2.
#define CW 16

__device__ __forceinline__ float softmin2(float a, float b, float c)
{
  float m  = fminf(fminf(a, b), c);                 // v_min3
  float md = __builtin_amdgcn_fmed3f(a, b, c);     // v_med3
  float M  = fmaxf(fmaxf(a, b), c);                 // v_max3
  float s = 1.0f + __builtin_amdgcn_exp2f(m - md) + __builtin_amdgcn_exp2f(m - M);
  return m - __builtin_amdgcn_logf(s);              // v_log_f32 = log2
}

__device__ __forceinline__ void dp_step2(int d, int t, int lane, int w,
                                         __half2 delh, const float* ebprev,
                                         float* ebrow,
                                         float& clo, float& chi, float& clo2, float& n2)
{
  float nb = __shfl_up(chi, 1);
  if (lane == 0) {
    float ev = BIGF;
    if (w) ev = ebprev[(d - 1) & 63];
    nb = ev;
  }
  float2 del = __half22float2(delh);
  int jlo = d - 2 * t;
  float lo = del.x + softmin2(n2, nb, clo);
  lo = ((unsigned)jlo < 512u) ? lo : BIGF;
  float hi = del.y + softmin2(clo2, clo, chi);
  hi = ((unsigned)(jlo - 1) < 512u) ? hi : BIGF;
  n2 = nb; clo2 = clo; clo = lo; chi = hi;
  if (lane == 63) ebrow[d & 63] = hi;
}

__global__ __launch_bounds__(256, 1)
void dp_kernel(const __half2* __restrict__ skew, float* __restrict__ loss)
{
  __shared__ float ebuf[4][64];
  const int b = blockIdx.x;
  const int t = threadIdx.x;
  const int lane = t & 63;
  const int w = t >> 6;

  ((float*)ebuf)[t] = BIGF;
  __syncthreads();

  const __half2* base = skew + (size_t)b * 1023 * 256 + t;
  float* ebrow = ebuf[w];
  const float* ebprev = (w > 0) ? ebuf[w - 1] : ebuf[0];

  float clo = BIGF, chi = BIGF, clo2 = BIGF;
  float n2 = (t == 0) ? 0.f : BIGF;      // corner R[-1][-1]=0 at d=0
  const int wC = w * CW;

  __half2 pfA[CW], pfB[CW];
  #pragma unroll
  for (int q = 0; q < CW; ++q) {
    int d = q - wC; int dc = d < 0 ? 0 : (d > 1022 ? 1022 : d);
    pfA[q] = base[(size_t)dc * 256];
  }

  // S_total = 1088 >= 1022 + 3*CW + 1; two chunks per outer iteration
  for (int sb = 0; sb < 1088; sb += 2 * CW) {
    #pragma unroll
    for (int q = 0; q < CW; ++q) {
      int dn = sb + CW + q - wC; int dc = dn < 0 ? 0 : (dn > 1022 ? 1022 : dn);
      pfB[q] = base[(size_t)dc * 256];
      int d = sb + q - wC;
      if ((unsigned)d <= 1022u)
        dp_step2(d, t, lane, w, pfA[q], ebprev, ebrow, clo, chi, clo2, n2);
    }
    __syncthreads();
    #pragma unroll
    for (int q = 0; q < CW; ++q) {
      int dn = sb + 2 * CW + q - wC; int dc = dn < 0 ? 0 : (dn > 1022 ? 1022 : dn);
      pfA[q] = base[(size_t)dc * 256];
      int d = sb + CW + q - wC;
      if ((unsigned)d <= 1022u)
        dp_step2(d, t, lane, w, pfB[q], ebprev, ebrow, clo, chi, clo2, n2);
    }
    __syncthreads();
  }

  if (t == 255) loss[b] = chi * LN2;     // R[511][511]
}

// ======================= Fallback (round-1 kernel) =======================
#define DQ 16
#define YST 68

__device__ __forceinline__ void fb_step(
    const int d, const int t, const float4* __restrict__ xr, const float xx,
    const float* __restrict__ ylds,
    const float* __restrict__ a1, const float* __restrict__ a2,
    float* __restrict__ aw, float& myP1)
{
  const int j = d - t;
  const bool valid = (j >= 0) && (j < NN);
  float dd = 0.f;
  if (valid) {
    const float* yrow = &ylds[j * YST];
    float ax = 0.f, ay = 0.f, az = 0.f, aww = 0.f;
    #pragma unroll
    for (int k = 0; k < DQ; ++k) {
      float4 v = *(const float4*)(yrow + 4 * k);
      ax  = fmaf(xr[k].x, v.x, ax);
      ay  = fmaf(xr[k].y, v.y, ay);
      az  = fmaf(xr[k].z, v.z, az);
      aww = fmaf(xr[k].w, v.w, aww);
    }
    float dot = (ax + ay) + (az + aww);
    dd = fmaf(-2.f, dot, xx + yrow[DD]);
  }
  float p1m1 = a1[t];
  float p2m1 = a2[t];
  if (t == 0) p2m1 = (d == 0) ? 0.f : BIGF;
  float m = fminf(fminf(p2m1, p1m1), myP1);
  float s = __expf(m - p2m1) + __expf(m - p1m1) + __expf(m - myP1);
  float sm = m - __logf(s);
  float cur = valid ? (dd + sm) : BIGF;
  aw[t + 1] = cur;
  myP1 = cur;
  __syncthreads();
}

__global__ __launch_bounds__(512, 2)
void dtw_fallback_kernel(const float* __restrict__ X, const float* __restrict__ Y,
                         float* __restrict__ loss)
{
  __shared__ float ylds[NN * YST];
  __shared__ float diag[3][NN + 1];

  const int b = blockIdx.x;
  const int t = threadIdx.x;

  const float4* Y4 = (const float4*)(Y + (size_t)b * NN * DD);
  for (int idx = t; idx < NN * DQ; idx += NN) {
    float4 v = Y4[idx];
    *(float4*)&ylds[(idx >> 4) * YST + (idx & 15) * 4] = v;
  }
  diag[0][t + 1] = BIGF; diag[1][t + 1] = BIGF; diag[2][t + 1] = BIGF;
  if (t == 0) { diag[0][0] = BIGF; diag[1][0] = BIGF; diag[2][0] = BIGF; }
  __syncthreads();

  float4 xr[DQ];
  float xx = 0.f;
  const float4* X4 = (const float4*)(X + (size_t)b * NN * DD + (size_t)t * DD);
  #pragma unroll
  for (int k = 0; k < DQ; ++k) {
    float4 v = X4[k];
    xr[k] = v;
    xx += v.x * v.x + v.y * v.y + v.z * v.z + v.w * v.w;
  }
  {
    float s = 0.f;
    const float* yrow = &ylds[t * YST];
    #pragma unroll
    for (int k = 0; k < DQ; ++k) {
      float4 v = *(const float4*)(yrow + 4 * k);
      s += v.x * v.x + v.y * v.y + v.z * v.z + v.w * v.w;
    }
    ylds[t * YST + DD] = s;
  }
  __syncthreads();

  float myP1 = BIGF;
  for (int dbase = 0; dbase < 2 * NN - 1; dbase += 3) {
    fb_step(dbase,     t, xr, xx, ylds, diag[2], diag[1], diag[0], myP1);
    fb_step(dbase + 1, t, xr, xx, ylds, diag[0], diag[2], diag[1], myP1);
    fb_step(dbase + 2, t, xr, xx, ylds, diag[1], diag[0], diag[2], myP1);
  }
  if (t == NN - 1) loss[b] = myP1;
}

// ======================= mean =======================
__global__ void mean_kernel(const float* __restrict__ loss, float* __restrict__ out, int B)
{
  const int t = threadIdx.x;
  float v = (t < B) ? loss[t] : 0.f;
  #pragma unroll
  for (int off = 32; off; off >>= 1) v += __shfl_down(v, off);
  if (t == 0) out[0] = v / (float)B;
}

extern "C" void kernel_launch(void* const* d_in, const int* in_sizes, int n_in,
                              void* d_out, int out_size, void* d_ws, size_t ws_size,
                              hipStream_t stream)
{
  const float* X = (const float*)d_in[0];
  const float* Y = (const float*)d_in[1];
  float* out = (float*)d_out;
  float* ws  = (float*)d_ws;

  const int B = in_sizes[0] / (NN * DD);   // 64

  const size_t skew_bytes = (size_t)B * (2 * NN - 1) * NN * sizeof(__half);
  const size_t need = skew_bytes + 256;

  if (ws_size >= need) {
    float*  loss = ws;                      // B floats
    __half* skew = (__half*)(ws + 64);      // 256B offset
    delta_kernel<<<dim3(NN / TS, NN / TS, B), 256, 0, stream>>>(X, Y, skew);
    dp_kernel<<<B, 256, 0, stream>>>((const __half2*)skew, loss);
    mean_kernel<<<1, 64, 0, stream>>>(loss, out, B);
  } else {
    dtw_fallback_kernel<<<B, NN, 0, stream>>>(X, Y, ws);
    mean_kernel<<<1, 64, 0, stream>>>(ws, out, B);
  }
}

// Round 4
// 195.515 us; speedup vs baseline: 1.6527x; 1.6527x over previous
//
#include <hip/hip_runtime.h>
#include <hip/hip_fp16.h>

#define NN 512          // N == M
#define DD 64           // feature dim
#define BIGF 1e10f
#define INV_LN2 1.44269504088896340736f
#define LN2 0.69314718055994530942f

// ======================= Phase 1: deltaT (row-major, fp16/ln2) =======================
// OUT[u][v] = ||A_u||^2 + ||B_v||^2 - 2 A_u.B_v, scaled by 1/ln2, fp16.
// Called with A = Y(target), B = X(input)  =>  OUT = deltaT[j][i] = delta[i][j].
#define TS 128
#define XST 68          // LDS stage row stride (floats)

__global__ __launch_bounds__(256, 2)
void delta_kernel(const float* __restrict__ A, const float* __restrict__ Bm,
                  __half* __restrict__ OUT)
{
  __shared__ __align__(16) float Xs[TS * XST];
  __shared__ __align__(16) float Ys[TS * XST];
  __shared__ float norms[2 * TS];                 // A-row norms | B-row norms

  const int bz = blockIdx.z;
  const int u0 = blockIdx.y * TS;
  const int v0 = blockIdx.x * TS;
  const int tid = threadIdx.x;

  const float4* A4 = (const float4*)(A  + ((size_t)bz * NN + u0) * DD);
  const float4* B4 = (const float4*)(Bm + ((size_t)bz * NN + v0) * DD);
  #pragma unroll
  for (int q = 0; q < 8; ++q) {
    int idx = tid + 256 * q;          // 0..2047
    int r = idx >> 4, c4 = idx & 15;
    *(float4*)&Xs[r * XST + 4 * c4] = A4[idx];
    *(float4*)&Ys[r * XST + 4 * c4] = B4[idx];
  }
  __syncthreads();

  {
    const float* row = (tid < TS) ? &Xs[tid * XST] : &Ys[(tid - TS) * XST];
    float s = 0.f;
    #pragma unroll
    for (int k4 = 0; k4 < 16; ++k4) {
      float4 v = *(const float4*)&row[4 * k4];
      s += v.x * v.x + v.y * v.y + v.z * v.z + v.w * v.w;
    }
    norms[tid] = s;
  }

  const int iB = (tid >> 4) * 8;      // A-row block within tile
  const int jB = (tid & 15) * 8;      // B-row block within tile
  float acc[8][8];
  #pragma unroll
  for (int a = 0; a < 8; ++a)
    #pragma unroll
    for (int c = 0; c < 8; ++c) acc[a][c] = 0.f;

  #pragma unroll
  for (int kc = 0; kc < 16; ++kc) {
    float4 xv[8], yv[8];
    #pragma unroll
    for (int a = 0; a < 8; ++a) xv[a] = *(const float4*)&Xs[(iB + a) * XST + 4 * kc];
    #pragma unroll
    for (int c = 0; c < 8; ++c) yv[c] = *(const float4*)&Ys[(jB + c) * XST + 4 * kc];
    #pragma unroll
    for (int a = 0; a < 8; ++a)
      #pragma unroll
      for (int c = 0; c < 8; ++c) {
        float4 xa = xv[a], yc = yv[c];
        acc[a][c] = fmaf(xa.x, yc.x,
                    fmaf(xa.y, yc.y,
                    fmaf(xa.z, yc.z,
                    fmaf(xa.w, yc.w, acc[a][c]))));
      }
  }
  __syncthreads();   // norms visible

  __half* outb = OUT + (size_t)bz * NN * NN;
  #pragma unroll
  for (int a = 0; a < 8; ++a) {
    float uu = norms[iB + a];
    float f[8];
    #pragma unroll
    for (int cc = 0; cc < 8; ++cc)
      f[cc] = fmaf(-2.f, acc[a][cc], uu + norms[TS + jB + cc]) * INV_LN2;
    __half2 h0 = __floats2half2_rn(f[0], f[1]);
    __half2 h1 = __floats2half2_rn(f[2], f[3]);
    __half2 h2 = __floats2half2_rn(f[4], f[5]);
    __half2 h3 = __floats2half2_rn(f[6], f[7]);
    uint4 pk;
    pk.x = *(unsigned*)&h0; pk.y = *(unsigned*)&h1;
    pk.z = *(unsigned*)&h2; pk.w = *(unsigned*)&h3;
    *(uint4*)&outb[(size_t)(u0 + iB + a) * NN + (v0 + jB)] = pk;
  }
}

// ======================= Phase 2: column-sweep DP, DPP neighbor exchange =======================
// 256 threads = 4 waves. Lane t owns rows 2t, 2t+1. At step s, column c = s - off(t),
// off(t) = l + 3*(l>>4) + 90*w. Up/diag neighbor (row 2t-1) values come via DPP row_shr:1
// of the neighbor's previous-step hi; lanes at 16-lane boundaries read an LDS ring
// (2-step prefetched). Values in log2 units (delta/ln2).
#define RST 68          // ring row stride (floats), padded
#define TOT 864         // 512 + max_off(342), rounded to 16

__device__ __forceinline__ float softmin2(float a, float b, float c)
{
  float m  = fminf(fminf(a, b), c);
  float md = __builtin_amdgcn_fmed3f(a, b, c);
  float M  = fmaxf(fmaxf(a, b), c);
  float s = 1.0f + __builtin_amdgcn_exp2f(m - md) + __builtin_amdgcn_exp2f(m - M);
  return m - __builtin_amdgcn_logf(s);            // log2
}

__global__ __launch_bounds__(256, 1)
void dp_kernel(const __half2* __restrict__ deltaT, float* __restrict__ loss)
{
  __shared__ float ringf[16 * RST];

  const int b = blockIdx.x;
  const int t = threadIdx.x;
  const int l = t & 63, w = t >> 6, u = t & 15, g = t >> 4;
  const int off = 90 * w + l + 3 * (l >> 4);

  for (int k = t; k < 16 * RST; k += 256) ringf[k] = BIGF;
  __syncthreads();

  const __half2* dcol = deltaT + (size_t)b * NN * 256 + t;   // + c*256 per column

  float aL0 = BIGF, aL1 = BIGF, hprev = BIGF, nbprev = BIGF;
  float last = BIGF;
  int c = -off;                               // column at step 0
  const int corner_c = (t == 0) ? 0 : (int)0x80000000;   // matches c only for t==0,c==0
  const bool isw = (u == 15) && (g < 15);

  __half2 pf[8];
  #pragma unroll
  for (int q = 0; q < 8; ++q) {
    int cq = c + q; cq = cq < 0 ? 0 : (cq > 511 ? 511 : cq);
    pf[q] = dcol[cq * 256];
  }
  float rv0 = ringf[g * RST + (c & 63)];
  float rv1 = ringf[g * RST + ((c + 1) & 63)];

  for (int sb = 0; sb < TOT; sb += 16) {
    #pragma unroll
    for (int q = 0; q < 16; ++q) {
      float2 del = __half22float2(pf[q & 7]);
      // neighbor up value R[2t-1][c]: DPP shift of neighbor's previous hi; ring at u==0
      int nb_i = __builtin_amdgcn_update_dpp(__float_as_int(rv0), __float_as_int(hprev),
                                             0x111 /*row_shr:1*/, 0xf, 0xf, false);
      float nbU = __int_as_float(nb_i);
      float nbD = (c == corner_c) ? 0.f : nbprev;   // R[2t-1][c-1]; corner R[-1][-1]=0
      float lo = del.x + softmin2(nbD, nbU, aL0);   // row 2t, col c
      float hi = del.y + softmin2(aL0, lo, aL1);    // row 2t+1, col c
      bool valid = ((unsigned)c < 512u);
      lo = valid ? lo : BIGF;
      hi = valid ? hi : BIGF;
      nbprev = nbU; aL0 = lo; aL1 = hi; hprev = hi;
      if (isw) ringf[(g + 1) * RST + (c & 63)] = hi;
      last = (c == 511) ? hi : last;
      // prefetches
      rv0 = rv1;
      rv1 = ringf[g * RST + ((c + 2) & 63)];
      int cp = c + 8; cp = cp < 0 ? 0 : (cp > 511 ? 511 : cp);
      pf[q & 7] = dcol[cp * 256];
      ++c;
    }
    __syncthreads();
  }

  if (t == 255) loss[b] = last * LN2;   // R[511][511]
}

// ======================= Fallback (round-1 kernel, tiny ws) =======================
#define DQ 16
#define YST 68

__device__ __forceinline__ void fb_step(
    const int d, const int t, const float4* __restrict__ xr, const float xx,
    const float* __restrict__ ylds,
    const float* __restrict__ a1, const float* __restrict__ a2,
    float* __restrict__ aw, float& myP1)
{
  const int j = d - t;
  const bool valid = (j >= 0) && (j < NN);
  float dd = 0.f;
  if (valid) {
    const float* yrow = &ylds[j * YST];
    float ax = 0.f, ay = 0.f, az = 0.f, aww = 0.f;
    #pragma unroll
    for (int k = 0; k < DQ; ++k) {
      float4 v = *(const float4*)(yrow + 4 * k);
      ax  = fmaf(xr[k].x, v.x, ax);
      ay  = fmaf(xr[k].y, v.y, ay);
      az  = fmaf(xr[k].z, v.z, az);
      aww = fmaf(xr[k].w, v.w, aww);
    }
    float dot = (ax + ay) + (az + aww);
    dd = fmaf(-2.f, dot, xx + yrow[DD]);
  }
  float p1m1 = a1[t];
  float p2m1 = a2[t];
  if (t == 0) p2m1 = (d == 0) ? 0.f : BIGF;
  float m = fminf(fminf(p2m1, p1m1), myP1);
  float s = __expf(m - p2m1) + __expf(m - p1m1) + __expf(m - myP1);
  float sm = m - __logf(s);
  float cur = valid ? (dd + sm) : BIGF;
  aw[t + 1] = cur;
  myP1 = cur;
  __syncthreads();
}

__global__ __launch_bounds__(512, 2)
void dtw_fallback_kernel(const float* __restrict__ X, const float* __restrict__ Y,
                         float* __restrict__ loss)
{
  __shared__ float ylds[NN * YST];
  __shared__ float diag[3][NN + 1];

  const int b = blockIdx.x;
  const int t = threadIdx.x;

  const float4* Y4 = (const float4*)(Y + (size_t)b * NN * DD);
  for (int idx = t; idx < NN * DQ; idx += NN) {
    float4 v = Y4[idx];
    *(float4*)&ylds[(idx >> 4) * YST + (idx & 15) * 4] = v;
  }
  diag[0][t + 1] = BIGF; diag[1][t + 1] = BIGF; diag[2][t + 1] = BIGF;
  if (t == 0) { diag[0][0] = BIGF; diag[1][0] = BIGF; diag[2][0] = BIGF; }
  __syncthreads();

  float4 xr[DQ];
  float xx = 0.f;
  const float4* X4 = (const float4*)(X + (size_t)b * NN * DD + (size_t)t * DD);
  #pragma unroll
  for (int k = 0; k < DQ; ++k) {
    float4 v = X4[k];
    xr[k] = v;
    xx += v.x * v.x + v.y * v.y + v.z * v.z + v.w * v.w;
  }
  {
    float s = 0.f;
    const float* yrow = &ylds[t * YST];
    #pragma unroll
    for (int k = 0; k < DQ; ++k) {
      float4 v = *(const float4*)(yrow + 4 * k);
      s += v.x * v.x + v.y * v.y + v.z * v.z + v.w * v.w;
    }
    ylds[t * YST + DD] = s;
  }
  __syncthreads();

  float myP1 = BIGF;
  for (int dbase = 0; dbase < 2 * NN - 1; dbase += 3) {
    fb_step(dbase,     t, xr, xx, ylds, diag[2], diag[1], diag[0], myP1);
    fb_step(dbase + 1, t, xr, xx, ylds, diag[0], diag[2], diag[1], myP1);
    fb_step(dbase + 2, t, xr, xx, ylds, diag[1], diag[0], diag[2], myP1);
  }
  if (t == NN - 1) loss[b] = myP1;
}

// ======================= mean =======================
__global__ void mean_kernel(const float* __restrict__ loss, float* __restrict__ out, int B)
{
  const int t = threadIdx.x;
  float v = (t < B) ? loss[t] : 0.f;
  #pragma unroll
  for (int off = 32; off; off >>= 1) v += __shfl_down(v, off);
  if (t == 0) out[0] = v / (float)B;
}

extern "C" void kernel_launch(void* const* d_in, const int* in_sizes, int n_in,
                              void* d_out, int out_size, void* d_ws, size_t ws_size,
                              hipStream_t stream)
{
  const float* X = (const float*)d_in[0];   // input  (x, rows i)
  const float* Y = (const float*)d_in[1];   // target (y, rows j)
  float* out = (float*)d_out;
  float* ws  = (float*)d_ws;

  const int B = in_sizes[0] / (NN * DD);    // 64

  const size_t dT_bytes = (size_t)B * NN * NN * sizeof(__half);
  const size_t need = dT_bytes + 256;

  if (ws_size >= need) {
    float*  loss   = ws;                    // B floats
    __half* deltaT = (__half*)(ws + 64);    // 256B offset
    // OUT[u=j][v=i] = deltaT
    delta_kernel<<<dim3(NN / TS, NN / TS, B), 256, 0, stream>>>(Y, X, deltaT);
    dp_kernel<<<B, 256, 0, stream>>>((const __half2*)deltaT, loss);
    mean_kernel<<<1, 64, 0, stream>>>(loss, out, B);
  } else {
    dtw_fallback_kernel<<<B, NN, 0, stream>>>(X, Y, ws);
    mean_kernel<<<1, 64, 0, stream>>>(ws, out, B);
  }
}

// Round 5
// 158.463 us; speedup vs baseline: 2.0391x; 1.2338x over previous
//
#include <hip/hip_runtime.h>
#include <hip/hip_fp16.h>

#define NN 512          // N == M
#define DD 64           // feature dim
#define BIGF 1e10f
#define INV_LN2 1.44269504088896340736f
#define LN2 0.69314718055994530942f

// DP schedule constants (shared by both kernels)
// thread t in [0,256) owns rows 2t,2t+1; off(t) = 90*(t>>6) + l + 3*(l>>4), l=t&63
// S[s][t] = half2( delta[2t][c], delta[2t+1][c] ) / ln2, c = s - off(t)
#define SROWS 880       // >= 864 + 8 prefetch + margin
#define TOT 864         // 512 + max off (342), rounded to 16

// ======================= Phase 1: delta -> schedule-order S layout =======================
#define TS 128
#define XST 68          // LDS stage row stride (floats)
#define LST 65          // Ls row stride (dwords)

__global__ __launch_bounds__(256, 2)
void delta_kernel(const float* __restrict__ A, const float* __restrict__ Bm,
                  unsigned* __restrict__ S)   // S as uint (= half2) [b][SROWS][256]
{
  __shared__ __align__(16) float smem[2 * TS * XST];   // Xs|Ys, overlaid by Ls
  __shared__ float norms[2 * TS];                      // A-row norms | B-row norms
  float* Xs = smem;                   // [TS][XST]  A rows (= DP columns j)
  float* Ys = smem + TS * XST;        // [TS][XST]  B rows (= DP rows i)
  unsigned* Ls = (unsigned*)smem;     // [200][LST] parallelogram re-stage

  const int bz = blockIdx.z;
  const int u0 = blockIdx.y * TS;     // j tile base
  const int v0 = blockIdx.x * TS;     // i tile base
  const int tid = threadIdx.x;
  const int W  = blockIdx.x;          // wave index of this t-block (T0 = 64*W)
  const int T0 = v0 >> 1;

  const float4* A4 = (const float4*)(A  + ((size_t)bz * NN + u0) * DD);
  const float4* B4 = (const float4*)(Bm + ((size_t)bz * NN + v0) * DD);
  #pragma unroll
  for (int q = 0; q < 8; ++q) {
    int idx = tid + 256 * q;          // 0..2047
    int r = idx >> 4, c4 = idx & 15;
    *(float4*)&Xs[r * XST + 4 * c4] = A4[idx];
    *(float4*)&Ys[r * XST + 4 * c4] = B4[idx];
  }
  __syncthreads();

  {
    const float* row = (tid < TS) ? &Xs[tid * XST] : &Ys[(tid - TS) * XST];
    float s = 0.f;
    #pragma unroll
    for (int k4 = 0; k4 < 16; ++k4) {
      float4 v = *(const float4*)&row[4 * k4];
      s += v.x * v.x + v.y * v.y + v.z * v.z + v.w * v.w;
    }
    norms[tid] = s;
  }

  const int iB = (tid >> 4) * 8;      // j offset block
  const int jB = (tid & 15) * 8;      // i offset block
  float acc[8][8];
  #pragma unroll
  for (int a = 0; a < 8; ++a)
    #pragma unroll
    for (int c = 0; c < 8; ++c) acc[a][c] = 0.f;

  #pragma unroll
  for (int kc = 0; kc < 16; ++kc) {
    float4 xv[8], yv[8];
    #pragma unroll
    for (int a = 0; a < 8; ++a) xv[a] = *(const float4*)&Xs[(iB + a) * XST + 4 * kc];
    #pragma unroll
    for (int c = 0; c < 8; ++c) yv[c] = *(const float4*)&Ys[(jB + c) * XST + 4 * kc];
    #pragma unroll
    for (int a = 0; a < 8; ++a)
      #pragma unroll
      for (int c = 0; c < 8; ++c) {
        float4 xa = xv[a], yc = yv[c];
        acc[a][c] = fmaf(xa.x, yc.x,
                    fmaf(xa.y, yc.y,
                    fmaf(xa.z, yc.z,
                    fmaf(xa.w, yc.w, acc[a][c]))));
      }
  }
  __syncthreads();   // Xs/Ys dead; norms visible; Ls may overwrite

  // scatter into Ls: slot [s_local][t_local], s_local = (j-u0) + off_local(t_local)
  const int tl0 = (tid & 15) * 4;              // t_local for p=0
  const int sh  = 3 * ((tid & 15) >> 2);       // 3*(t_local>>4), same for p=0..3
  #pragma unroll
  for (int a = 0; a < 8; ++a) {
    float uu = norms[iB + a];
    float f[8];
    #pragma unroll
    for (int cc = 0; cc < 8; ++cc)
      f[cc] = fmaf(-2.f, acc[a][cc], uu + norms[TS + jB + cc]) * INV_LN2;
    #pragma unroll
    for (int p = 0; p < 4; ++p) {
      __half2 h = __floats2half2_rn(f[2 * p], f[2 * p + 1]);   // (even i, odd i)
      int tl = tl0 + p;
      int sl = iB + a + tl + sh;               // s_local
      Ls[sl * LST + tl] = *(unsigned*)&h;
    }
  }
  __syncthreads();

  // predicated coalesced write-out: row r covers global s = s_base + r
  const int tl = tid & 63;                      // t_local
  const int offl = tl + 3 * (tl >> 4);          // off_local(t_local)
  const int s_base = u0 + 90 * W;
  unsigned* Sb = S + (size_t)bz * SROWS * 256 + T0 + tl;
  for (int r0 = 0; r0 < 200; r0 += 4) {
    int r = r0 + (tid >> 6);
    int jr = r - offl;
    if ((unsigned)jr < 128u)
      Sb[(size_t)(s_base + r) * 256] = Ls[r * LST + tl];
  }
}

// ======================= Phase 2: column-sweep DP, coalesced delta =======================
#define RST 68          // ring row stride (floats), padded

__device__ __forceinline__ float softmin2(float a, float b, float c)
{
  float m  = fminf(fminf(a, b), c);
  float md = __builtin_amdgcn_fmed3f(a, b, c);
  float M  = fmaxf(fmaxf(a, b), c);
  float s = 1.0f + __builtin_amdgcn_exp2f(m - md) + __builtin_amdgcn_exp2f(m - M);
  return m - __builtin_amdgcn_logf(s);            // log2
}

__global__ __launch_bounds__(256, 1)
void dp_kernel(const __half2* __restrict__ S, float* __restrict__ loss)
{
  __shared__ float ringf[16 * RST];

  const int b = blockIdx.x;
  const int t = threadIdx.x;
  const int l = t & 63, w = t >> 6, u = t & 15, g = t >> 4;
  const int off = 90 * w + l + 3 * (l >> 4);

  for (int k = t; k < 16 * RST; k += 256) ringf[k] = BIGF;
  __syncthreads();

  const __half2* Sb = S + (size_t)b * SROWS * 256 + t;   // + s*256 per step

  float aL0 = BIGF, aL1 = BIGF, hprev = BIGF, nbprev = BIGF;
  float last = BIGF;
  int c = -off;                               // column at step 0
  const int corner_c = (t == 0) ? 0 : (int)0x80000000;
  const bool isw = (u == 15) && (g < 15);

  __half2 pf[8];
  #pragma unroll
  for (int q = 0; q < 8; ++q) pf[q] = Sb[(size_t)q * 256];
  float rv0 = ringf[g * RST + (c & 63)];
  float rv1 = ringf[g * RST + ((c + 1) & 63)];

  for (int sb = 0; sb < TOT; sb += 16) {
    #pragma unroll
    for (int q = 0; q < 16; ++q) {
      const int sidx = sb + q;
      float2 del = __half22float2(pf[sidx & 7]);
      // neighbor up value R[2t-1][c]: DPP shift of neighbor's previous hi; ring at u==0
      int nb_i = __builtin_amdgcn_update_dpp(__float_as_int(rv0), __float_as_int(hprev),
                                             0x111 /*row_shr:1*/, 0xf, 0xf, false);
      float nbU = __int_as_float(nb_i);
      float nbD = (c == corner_c) ? 0.f : nbprev;   // R[2t-1][c-1]; corner R[-1][-1]=0
      float lo = del.x + softmin2(nbD, nbU, aL0);   // row 2t, col c
      float hi = del.y + softmin2(aL0, lo, aL1);    // row 2t+1, col c
      bool valid = ((unsigned)c < 512u);
      lo = valid ? lo : BIGF;
      hi = valid ? hi : BIGF;
      nbprev = nbU; aL0 = lo; aL1 = hi; hprev = hi;
      if (isw) ringf[(g + 1) * RST + (c & 63)] = hi;
      last = (c == 511) ? hi : last;
      // prefetches
      rv0 = rv1;
      rv1 = ringf[g * RST + ((c + 2) & 63)];
      pf[sidx & 7] = Sb[(size_t)(sidx + 8) * 256];
      ++c;
    }
    __syncthreads();
  }

  if (t == 255) loss[b] = last * LN2;   // R[511][511]
}

// ======================= Fallback (round-1 kernel, tiny ws) =======================
#define DQ 16
#define YST 68

__device__ __forceinline__ void fb_step(
    const int d, const int t, const float4* __restrict__ xr, const float xx,
    const float* __restrict__ ylds,
    const float* __restrict__ a1, const float* __restrict__ a2,
    float* __restrict__ aw, float& myP1)
{
  const int j = d - t;
  const bool valid = (j >= 0) && (j < NN);
  float dd = 0.f;
  if (valid) {
    const float* yrow = &ylds[j * YST];
    float ax = 0.f, ay = 0.f, az = 0.f, aww = 0.f;
    #pragma unroll
    for (int k = 0; k < DQ; ++k) {
      float4 v = *(const float4*)(yrow + 4 * k);
      ax  = fmaf(xr[k].x, v.x, ax);
      ay  = fmaf(xr[k].y, v.y, ay);
      az  = fmaf(xr[k].z, v.z, az);
      aww = fmaf(xr[k].w, v.w, aww);
    }
    float dot = (ax + ay) + (az + aww);
    dd = fmaf(-2.f, dot, xx + yrow[DD]);
  }
  float p1m1 = a1[t];
  float p2m1 = a2[t];
  if (t == 0) p2m1 = (d == 0) ? 0.f : BIGF;
  float m = fminf(fminf(p2m1, p1m1), myP1);
  float s = __expf(m - p2m1) + __expf(m - p1m1) + __expf(m - myP1);
  float sm = m - __logf(s);
  float cur = valid ? (dd + sm) : BIGF;
  aw[t + 1] = cur;
  myP1 = cur;
  __syncthreads();
}

__global__ __launch_bounds__(512, 2)
void dtw_fallback_kernel(const float* __restrict__ X, const float* __restrict__ Y,
                         float* __restrict__ loss)
{
  __shared__ float ylds[NN * YST];
  __shared__ float diag[3][NN + 1];

  const int b = blockIdx.x;
  const int t = threadIdx.x;

  const float4* Y4 = (const float4*)(Y + (size_t)b * NN * DD);
  for (int idx = t; idx < NN * DQ; idx += NN) {
    float4 v = Y4[idx];
    *(float4*)&ylds[(idx >> 4) * YST + (idx & 15) * 4] = v;
  }
  diag[0][t + 1] = BIGF; diag[1][t + 1] = BIGF; diag[2][t + 1] = BIGF;
  if (t == 0) { diag[0][0] = BIGF; diag[1][0] = BIGF; diag[2][0] = BIGF; }
  __syncthreads();

  float4 xr[DQ];
  float xx = 0.f;
  const float4* X4 = (const float4*)(X + (size_t)b * NN * DD + (size_t)t * DD);
  #pragma unroll
  for (int k = 0; k < DQ; ++k) {
    float4 v = X4[k];
    xr[k] = v;
    xx += v.x * v.x + v.y * v.y + v.z * v.z + v.w * v.w;
  }
  {
    float s = 0.f;
    const float* yrow = &ylds[t * YST];
    #pragma unroll
    for (int k = 0; k < DQ; ++k) {
      float4 v = *(const float4*)(yrow + 4 * k);
      s += v.x * v.x + v.y * v.y + v.z * v.z + v.w * v.w;
    }
    ylds[t * YST + DD] = s;
  }
  __syncthreads();

  float myP1 = BIGF;
  for (int dbase = 0; dbase < 2 * NN - 1; dbase += 3) {
    fb_step(dbase,     t, xr, xx, ylds, diag[2], diag[1], diag[0], myP1);
    fb_step(dbase + 1, t, xr, xx, ylds, diag[0], diag[2], diag[1], myP1);
    fb_step(dbase + 2, t, xr, xx, ylds, diag[1], diag[0], diag[2], myP1);
  }
  if (t == NN - 1) loss[b] = myP1;
}

// ======================= mean =======================
__global__ void mean_kernel(const float* __restrict__ loss, float* __restrict__ out, int B)
{
  const int t = threadIdx.x;
  float v = (t < B) ? loss[t] : 0.f;
  #pragma unroll
  for (int off = 32; off; off >>= 1) v += __shfl_down(v, off);
  if (t == 0) out[0] = v / (float)B;
}

extern "C" void kernel_launch(void* const* d_in, const int* in_sizes, int n_in,
                              void* d_out, int out_size, void* d_ws, size_t ws_size,
                              hipStream_t stream)
{
  const float* X = (const float*)d_in[0];   // input  (x, DP rows i)
  const float* Y = (const float*)d_in[1];   // target (y, DP cols j)
  float* out = (float*)d_out;
  float* ws  = (float*)d_ws;

  const int B = in_sizes[0] / (NN * DD);    // 64

  const size_t S_bytes = (size_t)B * SROWS * 256 * 4;
  const size_t need = S_bytes + 256;

  if (ws_size >= need) {
    float*    loss = ws;                    // B floats
    unsigned* S    = (unsigned*)(ws + 64);  // 256B offset, [b][SROWS][256] half2
    // A = Y (j rows), B = X (i rows)
    delta_kernel<<<dim3(NN / TS, NN / TS, B), 256, 0, stream>>>(Y, X, S);
    dp_kernel<<<B, 256, 0, stream>>>((const __half2*)S, loss);
    mean_kernel<<<1, 64, 0, stream>>>(loss, out, B);
  } else {
    dtw_fallback_kernel<<<B, NN, 0, stream>>>(X, Y, ws);
    mean_kernel<<<1, 64, 0, stream>>>(ws, out, B);
  }
}

// Round 6
// 146.404 us; speedup vs baseline: 2.2071x; 1.0824x over previous
//
#include <hip/hip_runtime.h>
#include <hip/hip_fp16.h>

#define NN 512          // N == M
#define DD 64           // feature dim
#define BIGF 1e10f
#define INV_LN2 1.44269504088896340736f
#define LN2 0.69314718055994530942f

// DP schedule (shared by both kernels):
// 256 threads = 4 waves; thread t owns rows 2t, 2t+1; l = t&63, w = t>>6.
// off(t) = l + 80*w  (uniform stagger; wave lag 80, in-wave lag 1)
// At step s, lane t processes column c = s - off(t).
// S[s][t] = half2( delta[2t][c], delta[2t+1][c] ) / ln2.
#define W0 80
#define TOTM 800        // 50 full 16-step blocks
#define EPI 15          // +15 epilogue steps -> last step s = 814
#define SROWS 832       // >= 814 + 8 prefetch + margin

// ======================= Phase 1: delta -> schedule-order S =======================
#define TS 128
#define XST 68          // LDS stage row stride (floats)
#define LST 66          // Ls row stride (dwords); chosen to cut scatter conflicts

__global__ __launch_bounds__(256, 2)
void delta_kernel(const float* __restrict__ A, const float* __restrict__ Bm,
                  unsigned* __restrict__ S)   // S as uint (= half2) [b][SROWS][256]
{
  __shared__ __align__(16) float smem[2 * TS * XST];   // Xs|Ys, overlaid by Ls
  __shared__ float norms[2 * TS];                      // A-row norms | B-row norms
  float* Xs = smem;                   // [TS][XST]  A rows (= DP columns j)
  float* Ys = smem + TS * XST;        // [TS][XST]  B rows (= DP rows i)
  unsigned* Ls = (unsigned*)smem;     // [191][LST] parallelogram re-stage

  const int bz = blockIdx.z;
  const int u0 = blockIdx.y * TS;     // j tile base
  const int v0 = blockIdx.x * TS;     // i tile base
  const int bx = blockIdx.x;          // wave index of this t-range (T0 = 64*bx)
  const int tid = threadIdx.x;
  const int T0 = v0 >> 1;

  const float4* A4 = (const float4*)(A  + ((size_t)bz * NN + u0) * DD);
  const float4* B4 = (const float4*)(Bm + ((size_t)bz * NN + v0) * DD);
  #pragma unroll
  for (int q = 0; q < 8; ++q) {
    int idx = tid + 256 * q;          // 0..2047
    int r = idx >> 4, c4 = idx & 15;
    *(float4*)&Xs[r * XST + 4 * c4] = A4[idx];
    *(float4*)&Ys[r * XST + 4 * c4] = B4[idx];
  }
  __syncthreads();

  {
    const float* row = (tid < TS) ? &Xs[tid * XST] : &Ys[(tid - TS) * XST];
    float s = 0.f;
    #pragma unroll
    for (int k4 = 0; k4 < 16; ++k4) {
      float4 v = *(const float4*)&row[4 * k4];
      s += v.x * v.x + v.y * v.y + v.z * v.z + v.w * v.w;
    }
    norms[tid] = s;
  }

  const int iB = (tid >> 4) * 8;      // j-offset block
  const int jB = (tid & 15) * 8;      // i-offset block
  float acc[8][8];
  #pragma unroll
  for (int a = 0; a < 8; ++a)
    #pragma unroll
    for (int c = 0; c < 8; ++c) acc[a][c] = 0.f;

  #pragma unroll
  for (int kc = 0; kc < 16; ++kc) {
    float4 xv[8], yv[8];
    #pragma unroll
    for (int a = 0; a < 8; ++a) xv[a] = *(const float4*)&Xs[(iB + a) * XST + 4 * kc];
    #pragma unroll
    for (int c = 0; c < 8; ++c) yv[c] = *(const float4*)&Ys[(jB + c) * XST + 4 * kc];
    #pragma unroll
    for (int a = 0; a < 8; ++a)
      #pragma unroll
      for (int c = 0; c < 8; ++c) {
        float4 xa = xv[a], yc = yv[c];
        acc[a][c] = fmaf(xa.x, yc.x,
                    fmaf(xa.y, yc.y,
                    fmaf(xa.z, yc.z,
                    fmaf(xa.w, yc.w, acc[a][c]))));
      }
  }
  __syncthreads();   // Xs/Ys dead; norms visible; Ls may overwrite

  // scatter into Ls: t_local tl = (jB + cc)>>1 = tl0 + p; s_local = (iB+a) + tl
  const int tl0 = (tid & 15) * 4;
  #pragma unroll
  for (int a = 0; a < 8; ++a) {
    float uu = norms[iB + a];
    float f[8];
    #pragma unroll
    for (int cc = 0; cc < 8; ++cc)
      f[cc] = fmaf(-2.f, acc[a][cc], uu + norms[TS + jB + cc]) * INV_LN2;
    #pragma unroll
    for (int p = 0; p < 4; ++p) {
      __half2 h = __floats2half2_rn(f[2 * p], f[2 * p + 1]);   // (even i, odd i)
      int tl = tl0 + p;
      int sl = iB + a + tl;                    // s_local in [0, 191)
      Ls[sl * LST + tl] = *(unsigned*)&h;
    }
  }
  __syncthreads();

  // coalesced write-out: row r covers global s = s_base + r; valid iff (r - tl) in [0,128)
  const int tl = tid & 63;
  const int s_base = u0 + W0 * bx;
  unsigned* Sb = S + (size_t)bz * SROWS * 256 + T0 + tl;
  for (int r0 = 0; r0 < 191; r0 += 4) {
    int r = r0 + (tid >> 6);
    int jr = r - tl;
    if (r < 191 && (unsigned)jr < 128u)
      Sb[(size_t)(s_base + r) * 256] = Ls[r * LST + tl];
  }
}

// ======================= Phase 2: column-sweep DP, all-register neighbor path =======================
__device__ __forceinline__ float softmin2(float a, float b, float c)
{
  float m  = fminf(fminf(a, b), c);
  float md = __builtin_amdgcn_fmed3f(a, b, c);
  float M  = fmaxf(fmaxf(a, b), c);
  float s = 1.0f + __builtin_amdgcn_exp2f(m - md) + __builtin_amdgcn_exp2f(m - M);
  return m - __builtin_amdgcn_logf(s);            // log2 domain
}

__global__ __launch_bounds__(256, 1)
void dp_kernel(const __half2* __restrict__ S, float* __restrict__ loss)
{
  __shared__ float ring[4 * 32];     // per-wave boundary ring; row 0 stays BIG

  const int b = blockIdx.x;
  const int t = threadIdx.x;
  const int l = t & 63, w = t >> 6;
  const int off = l + W0 * w;

  if (t < 128) ring[t] = BIGF;
  __syncthreads();

  const bool is_u0 = ((l & 15) == 0) && (l != 0);   // lanes 16,32,48: row_bcast15 path
  const bool is_l0 = (l == 0);                      // wave boundary: SGPR ring path
  const bool isw   = (l == 63) && (w < 3);          // ring writer

  const __half2* Sb = S + (size_t)b * SROWS * 256 + t;

  float aL0 = BIGF, aL1 = BIGF, hprev = BIGF;
  float nbprev = (t == 0) ? 0.f : BIGF;   // corner R[-1][-1] = 0 folded into init
  int c = -off;

  __half2 pf[8];
  #pragma unroll
  for (int q = 0; q < 8; ++q) pf[q] = Sb[(size_t)q * 256];

#define DP_STEP(SIDX)                                                          \
  {                                                                            \
    float2 del = __half22float2(pf[(SIDX) & 7]);                               \
    int shr = __builtin_amdgcn_update_dpp(__float_as_int(hprev),               \
               __float_as_int(hprev), 0x111, 0xF, 0xF, false);                 \
    int bc  = __builtin_amdgcn_update_dpp(__float_as_int(hprev),               \
               __float_as_int(hprev), 0x142, 0xF, 0xF, false);                 \
    float nbU = __int_as_float(shr);                                           \
    nbU = is_u0 ? __int_as_float(bc) : nbU;                                    \
    nbU = is_l0 ? srq : nbU;                                                   \
    float lo = del.x + softmin2(nbprev, nbU, aL0);                             \
    float hi = del.y + softmin2(aL0, lo, aL1);                                 \
    bool valid = ((unsigned)c < 512u);                                         \
    lo = valid ? lo : BIGF;                                                    \
    hi = valid ? hi : BIGF;                                                    \
    nbprev = nbU; aL0 = lo; aL1 = hi; hprev = hi;                              \
    if (isw) ring[(w + 1) * 32 + (c & 31)] = hi;                               \
    pf[(SIDX) & 7] = Sb[(size_t)((SIDX) + 8) * 256];                           \
    ++c;                                                                       \
  }

  for (int sb = 0; sb < TOTM; sb += 16) {
    // batched boundary values for this block (written >= 2 steps before the barrier)
    int c0 = sb - W0 * w;
    float ringv = ring[w * 32 + ((c0 + (l & 15)) & 31)];
    #pragma unroll
    for (int q = 0; q < 16; ++q) {
      float srq = __int_as_float(
          __builtin_amdgcn_readlane(__float_as_int(ringv), q));
      DP_STEP(sb + q)
    }
    __syncthreads();
  }
  { // epilogue: steps 800..814 (lane 255 finishes at c=511 exactly)
    int c0 = TOTM - W0 * w;
    float ringv = ring[w * 32 + ((c0 + (l & 15)) & 31)];
    #pragma unroll
    for (int q = 0; q < EPI; ++q) {
      float srq = __int_as_float(
          __builtin_amdgcn_readlane(__float_as_int(ringv), q));
      DP_STEP(TOTM + q)
    }
  }

  if (t == 255) loss[b] = aL1 * LN2;   // R[511][511]
}

// ======================= Fallback (round-1 kernel, tiny ws) =======================
#define DQ 16
#define YST 68

__device__ __forceinline__ void fb_step(
    const int d, const int t, const float4* __restrict__ xr, const float xx,
    const float* __restrict__ ylds,
    const float* __restrict__ a1, const float* __restrict__ a2,
    float* __restrict__ aw, float& myP1)
{
  const int j = d - t;
  const bool valid = (j >= 0) && (j < NN);
  float dd = 0.f;
  if (valid) {
    const float* yrow = &ylds[j * YST];
    float ax = 0.f, ay = 0.f, az = 0.f, aww = 0.f;
    #pragma unroll
    for (int k = 0; k < DQ; ++k) {
      float4 v = *(const float4*)(yrow + 4 * k);
      ax  = fmaf(xr[k].x, v.x, ax);
      ay  = fmaf(xr[k].y, v.y, ay);
      az  = fmaf(xr[k].z, v.z, az);
      aww = fmaf(xr[k].w, v.w, aww);
    }
    float dot = (ax + ay) + (az + aww);
    dd = fmaf(-2.f, dot, xx + yrow[DD]);
  }
  float p1m1 = a1[t];
  float p2m1 = a2[t];
  if (t == 0) p2m1 = (d == 0) ? 0.f : BIGF;
  float m = fminf(fminf(p2m1, p1m1), myP1);
  float s = __expf(m - p2m1) + __expf(m - p1m1) + __expf(m - myP1);
  float sm = m - __logf(s);
  float cur = valid ? (dd + sm) : BIGF;
  aw[t + 1] = cur;
  myP1 = cur;
  __syncthreads();
}

__global__ __launch_bounds__(512, 2)
void dtw_fallback_kernel(const float* __restrict__ X, const float* __restrict__ Y,
                         float* __restrict__ loss)
{
  __shared__ float ylds[NN * YST];
  __shared__ float diag[3][NN + 1];

  const int b = blockIdx.x;
  const int t = threadIdx.x;

  const float4* Y4 = (const float4*)(Y + (size_t)b * NN * DD);
  for (int idx = t; idx < NN * DQ; idx += NN) {
    float4 v = Y4[idx];
    *(float4*)&ylds[(idx >> 4) * YST + (idx & 15) * 4] = v;
  }
  diag[0][t + 1] = BIGF; diag[1][t + 1] = BIGF; diag[2][t + 1] = BIGF;
  if (t == 0) { diag[0][0] = BIGF; diag[1][0] = BIGF; diag[2][0] = BIGF; }
  __syncthreads();

  float4 xr[DQ];
  float xx = 0.f;
  const float4* X4 = (const float4*)(X + (size_t)b * NN * DD + (size_t)t * DD);
  #pragma unroll
  for (int k = 0; k < DQ; ++k) {
    float4 v = X4[k];
    xr[k] = v;
    xx += v.x * v.x + v.y * v.y + v.z * v.z + v.w * v.w;
  }
  {
    float s = 0.f;
    const float* yrow = &ylds[t * YST];
    #pragma unroll
    for (int k = 0; k < DQ; ++k) {
      float4 v = *(const float4*)(yrow + 4 * k);
      s += v.x * v.x + v.y * v.y + v.z * v.z + v.w * v.w;
    }
    ylds[t * YST + DD] = s;
  }
  __syncthreads();

  float myP1 = BIGF;
  for (int dbase = 0; dbase < 2 * NN - 1; dbase += 3) {
    fb_step(dbase,     t, xr, xx, ylds, diag[2], diag[1], diag[0], myP1);
    fb_step(dbase + 1, t, xr, xx, ylds, diag[0], diag[2], diag[1], myP1);
    fb_step(dbase + 2, t, xr, xx, ylds, diag[1], diag[0], diag[2], myP1);
  }
  if (t == NN - 1) loss[b] = myP1;
}

// ======================= mean =======================
__global__ void mean_kernel(const float* __restrict__ loss, float* __restrict__ out, int B)
{
  const int t = threadIdx.x;
  float v = (t < B) ? loss[t] : 0.f;
  #pragma unroll
  for (int off = 32; off; off >>= 1) v += __shfl_down(v, off);
  if (t == 0) out[0] = v / (float)B;
}

extern "C" void kernel_launch(void* const* d_in, const int* in_sizes, int n_in,
                              void* d_out, int out_size, void* d_ws, size_t ws_size,
                              hipStream_t stream)
{
  const float* X = (const float*)d_in[0];   // input  (x, DP rows i)
  const float* Y = (const float*)d_in[1];   // target (y, DP cols j)
  float* out = (float*)d_out;
  float* ws  = (float*)d_ws;

  const int B = in_sizes[0] / (NN * DD);    // 64

  const size_t S_bytes = (size_t)B * SROWS * 256 * 4;
  const size_t need = S_bytes + 256;

  if (ws_size >= need) {
    float*    loss = ws;                    // B floats
    unsigned* S    = (unsigned*)(ws + 64);  // 256B offset, [b][SROWS][256] half2
    // A = Y (j rows), B = X (i rows)
    delta_kernel<<<dim3(NN / TS, NN / TS, B), 256, 0, stream>>>(Y, X, S);
    dp_kernel<<<B, 256, 0, stream>>>((const __half2*)S, loss);
    mean_kernel<<<1, 64, 0, stream>>>(loss, out, B);
  } else {
    dtw_fallback_kernel<<<B, NN, 0, stream>>>(X, Y, ws);
    mean_kernel<<<1, 64, 0, stream>>>(ws, out, B);
  }
}